// Round 1
// baseline (274.664 us; speedup 1.0000x reference)
//
#include <hip/hip_runtime.h>

#define B_    4
#define L_    8192
#define D_    1024
#define ROWS_ 32768
#define NCH_  128   // chunks of 64 rows per sequence

typedef __attribute__((ext_vector_type(8))) short  short8;
typedef __attribute__((ext_vector_type(4))) float  floatx4;

__device__ __forceinline__ unsigned short f2bf(float f){
  unsigned int u = __float_as_uint(f);
  u += 0x7fffu + ((u >> 16) & 1u);   // round-to-nearest-even
  return (unsigned short)(u >> 16);
}

// ---------------------------------------------------------------------------
// K1: gate GEMV (4 dots of length 1024 per row) + chunk-local scan (64 rows)
// grid 512 blocks (b,chunk), 512 threads (8 waves x 8 rows each)
// ---------------------------------------------------------------------------
__global__ __launch_bounds__(512) void k_gates(
    const float* __restrict__ x,
    const float* __restrict__ inc_w, const float* __restrict__ inc_b,
    const float* __restrict__ reset_w, const float* __restrict__ reset_b,
    float* __restrict__ out_incl,
    float* __restrict__ cl, float* __restrict__ kc,
    float* __restrict__ sumP, float* __restrict__ sumQ)
{
  __shared__ float s_keep[128];
  __shared__ float s_inc[128];
  const int blk  = blockIdx.x;
  const int b    = blk >> 7;          // /NCH_
  const int ch   = blk & 127;
  const int tid  = threadIdx.x;
  const int w    = tid >> 6;
  const int lane = tid & 63;

  // per-lane weights for d in {i*256 + 4*lane .. +3}, both k, both gates
  float4 wia[4], wib[4], wra[4], wrb[4];
  #pragma unroll
  for (int i = 0; i < 4; ++i){
    const int d0 = i*256 + lane*4;
    const float4* pi = (const float4*)(inc_w + d0*2);
    wia[i] = pi[0]; wib[i] = pi[1];
    const float4* pr = (const float4*)(reset_w + d0*2);
    wra[i] = pr[0]; wrb[i] = pr[1];
  }
  const float bi0 = inc_b[0], bi1 = inc_b[1];
  const float br0 = reset_b[0], br1 = reset_b[1];

  const int row0 = b*L_ + ch*64 + w*8;
  float4 xc[4], xn[4];
  {
    const float4* xr = (const float4*)(x + (size_t)row0 * D_);
    #pragma unroll
    for (int i = 0; i < 4; ++i) xc[i] = xr[i*64 + lane];
  }
  #pragma unroll
  for (int r = 0; r < 8; ++r){
    if (r < 7){  // prefetch next row while computing this one
      const float4* xr = (const float4*)(x + (size_t)(row0 + r + 1) * D_);
      #pragma unroll
      for (int i = 0; i < 4; ++i) xn[i] = xr[i*64 + lane];
    }
    float ai0=0.f, ai1=0.f, ar0=0.f, ar1=0.f;
    #pragma unroll
    for (int i = 0; i < 4; ++i){
      const float4 v = xc[i];
      ai0 += v.x*wia[i].x + v.y*wia[i].z + v.z*wib[i].x + v.w*wib[i].z;
      ai1 += v.x*wia[i].y + v.y*wia[i].w + v.z*wib[i].y + v.w*wib[i].w;
      ar0 += v.x*wra[i].x + v.y*wra[i].z + v.z*wrb[i].x + v.w*wrb[i].z;
      ar1 += v.x*wra[i].y + v.y*wra[i].w + v.z*wrb[i].y + v.w*wrb[i].w;
    }
    #pragma unroll
    for (int m = 1; m < 64; m <<= 1){
      ai0 += __shfl_xor(ai0, m);
      ai1 += __shfl_xor(ai1, m);
      ar0 += __shfl_xor(ar0, m);
      ar1 += __shfl_xor(ar1, m);
    }
    if (lane == 0){
      const int row = row0 + r;
      const float il0 = ai0 + bi0, il1 = ai1 + bi1;
      const float rl0 = ar0 + br0, rl1 = ar1 + br1;
      out_incl[(size_t)row*2 + 0] = il0;
      out_incl[(size_t)row*2 + 1] = il1;
      const int lr = w*8 + r;
      s_inc [lr*2+0] = 1.f / (1.f + __expf(-il0));
      s_inc [lr*2+1] = 1.f / (1.f + __expf(-il1));
      s_keep[lr*2+0] = 1.f - 1.f / (1.f + __expf(-rl0));
      s_keep[lr*2+1] = 1.f - 1.f / (1.f + __expf(-rl1));
    }
    #pragma unroll
    for (int i = 0; i < 4; ++i) xc[i] = xn[i];
  }
  __syncthreads();

  // chunk-local inclusive scan: wave 0 -> k=0, wave 1 -> k=1, lane j = local row j
  if (tid < 128){
    const int k = w;
    float P = s_keep[lane*2 + k];   // keep
    float Q = s_inc [lane*2 + k];   // inc
    #pragma unroll
    for (int ofs = 1; ofs < 64; ofs <<= 1){
      const float Pp = __shfl_up(P, ofs);
      const float Qp = __shfl_up(Q, ofs);
      if (lane >= ofs){ Q = Q + P * Qp; P = P * Pp; }
    }
    const int row = b*L_ + ch*64 + lane;
    cl[(size_t)row*2 + k] = Q;      // zero-state local counter
    kc[(size_t)row*2 + k] = P;      // cumulative keep product
    if (lane == 63){
      const int seq = b*2 + k;
      sumP[seq*NCH_ + ch] = P;
      sumQ[seq*NCH_ + ch] = Q;
    }
  }
}

// ---------------------------------------------------------------------------
// K2: block 0 scans the 128 chunk summaries per sequence (8 waves = 8 seqs)
//     blocks 1..128 transpose+convert read_w (64x1024 f32) -> Bt (1024x64 bf16)
// ---------------------------------------------------------------------------
__global__ __launch_bounds__(512) void k_scan2(
    const float* __restrict__ sumP, const float* __restrict__ sumQ,
    float* __restrict__ carry,
    const float* __restrict__ read_w, unsigned short* __restrict__ Bt)
{
  if (blockIdx.x == 0){
    const int tid  = threadIdx.x;
    const int seq  = tid >> 6;     // 0..7 = (b*2+k)
    const int lane = tid & 63;
    const float* P0 = sumP + seq*NCH_;
    const float* Q0 = sumQ + seq*NCH_;
    float P = P0[lane], Q = Q0[lane];
    #pragma unroll
    for (int ofs = 1; ofs < 64; ofs <<= 1){
      const float Pp = __shfl_up(P, ofs);
      const float Qp = __shfl_up(Q, ofs);
      if (lane >= ofs){ Q = Q + P * Qp; P = P * Pp; }
    }
    if (lane == 0) carry[seq*NCH_ + 0] = 0.f;
    carry[seq*NCH_ + lane + 1] = Q;                // chunks 1..64
    const float Pc = __shfl(P, 63);
    const float Qc = __shfl(Q, 63);
    float P2 = P0[64 + lane], Q2 = Q0[64 + lane];
    #pragma unroll
    for (int ofs = 1; ofs < 64; ofs <<= 1){
      const float Pp = __shfl_up(P2, ofs);
      const float Qp = __shfl_up(Q2, ofs);
      if (lane >= ofs){ Q2 = Q2 + P2 * Qp; P2 = P2 * Pp; }
    }
    Q2 = Q2 + P2 * Qc;                             // fold in first-half total
    if (lane < 63) carry[seq*NCH_ + 65 + lane] = Q2;   // chunks 65..127
  } else {
    const int idx = (blockIdx.x - 1)*512 + threadIdx.x;  // 0..65535
    const int n  = idx >> 6;
    const int kk = idx & 63;
    Bt[idx] = f2bf(read_w[(size_t)kk*D_ + n]);
  }
}

// ---------------------------------------------------------------------------
// K3: carry fixup -> counters (output) -> sinusoidal emb (bf16, 32768x64)
// one wave per row (lane = emb column), 4 rows per wave
// ---------------------------------------------------------------------------
__global__ __launch_bounds__(256) void k_emb(
    const float* __restrict__ cl, const float* __restrict__ kc,
    const float* __restrict__ carry,
    float* __restrict__ out_cnt, unsigned short* __restrict__ emb)
{
  const int tid  = threadIdx.x;
  const int w    = tid >> 6;
  const int lane = tid & 63;
  const int gw   = blockIdx.x*4 + w;      // 0..8191
  const int k    = lane >> 5;
  const int idx  = lane & 31;
  const int f    = idx & 15;
  const float invf = exp2f(-0.8f * (float)f);   // 1/freqs[f], freqs=2^(12f/15)
  #pragma unroll
  for (int i = 0; i < 4; ++i){
    const int row = gw*4 + i;             // 0..32767
    const int b   = row >> 13;
    const int l   = row & (L_ - 1);
    const int ch  = l >> 6;
    const float c0 = cl[(size_t)row*2+0] + kc[(size_t)row*2+0]*carry[(b*2+0)*NCH_ + ch];
    const float c1 = cl[(size_t)row*2+1] + kc[(size_t)row*2+1]*carry[(b*2+1)*NCH_ + ch];
    if (lane == 0) out_cnt[(size_t)row*2+0] = c0;
    if (lane == 1) out_cnt[(size_t)row*2+1] = c1;
    const float c  = k ? c1 : c0;
    const float sc = c * invf;
    float rev = sc * 0.15915494309189535f;   // radians -> revolutions
    rev -= floorf(rev);
    const float e = (idx < 16) ? __builtin_amdgcn_sinf(rev)
                               : __builtin_amdgcn_cosf(rev);
    emb[(size_t)row*64 + lane] = f2bf(e);
  }
}

// ---------------------------------------------------------------------------
// K4: injection = emb(32768x64 bf16) @ read_w(64x1024) + read_b, via MFMA
// block = 4 waves; wave computes 16 rows x 64 cols (4 16x16 tiles, 2 k-steps)
// ---------------------------------------------------------------------------
__global__ __launch_bounds__(256) void k_gemm(
    const unsigned short* __restrict__ emb, const unsigned short* __restrict__ Bt,
    const float* __restrict__ read_b, float* __restrict__ out)
{
  const int tid  = threadIdx.x;
  const int w    = tid >> 6;
  const int lane = tid & 63;
  const int rb   = blockIdx.x >> 2;           // row tile 0..2047
  const int cb   = blockIdx.x & 3;            // col group
  const int rowBase = rb * 16;
  const int colBase = cb * 256 + w * 64;
  const int m    = lane & 15;
  const int quad = lane >> 4;

  // A fragments: A[m][k], m=lane&15, k=quad*8+j  (+32 for k-step 1)
  const short8* ap = (const short8*)(emb + (size_t)(rowBase + m) * 64);
  const short8 a0 = ap[quad];
  const short8 a1 = ap[4 + quad];

  floatx4 acc[4] = {{0.f,0.f,0.f,0.f},{0.f,0.f,0.f,0.f},
                    {0.f,0.f,0.f,0.f},{0.f,0.f,0.f,0.f}};
  #pragma unroll
  for (int ct = 0; ct < 4; ++ct){
    const int n = colBase + ct*16 + m;
    const short8* bp = (const short8*)(Bt + (size_t)n * 64);
    const short8 b0 = bp[quad];
    const short8 b1 = bp[4 + quad];
    acc[ct] = __builtin_amdgcn_mfma_f32_16x16x32_bf16(a0, b0, acc[ct], 0, 0, 0);
    acc[ct] = __builtin_amdgcn_mfma_f32_16x16x32_bf16(a1, b1, acc[ct], 0, 0, 0);
  }
  #pragma unroll
  for (int ct = 0; ct < 4; ++ct){
    const int col  = colBase + ct*16 + m;
    const float bias = read_b[col];
    #pragma unroll
    for (int r = 0; r < 4; ++r){
      const int row = rowBase + quad*4 + r;   // C/D: col=lane&15, row=quad*4+reg
      out[(size_t)row*D_ + col] = acc[ct][r] + bias;
    }
  }
}

// ---------------------------------------------------------------------------
extern "C" void kernel_launch(void* const* d_in, const int* in_sizes, int n_in,
                              void* d_out, int out_size, void* d_ws, size_t ws_size,
                              hipStream_t stream) {
  const float* x       = (const float*)d_in[0];
  const float* inc_w   = (const float*)d_in[1];
  const float* inc_b   = (const float*)d_in[2];
  const float* reset_w = (const float*)d_in[3];
  const float* reset_b = (const float*)d_in[4];
  const float* read_w  = (const float*)d_in[5];
  const float* read_b  = (const float*)d_in[6];

  float* out      = (float*)d_out;
  float* out_incl = out + (size_t)ROWS_ * D_;        // 33554432
  float* out_cnt  = out_incl + ROWS_ * 2;            // +65536

  char* ws = (char*)d_ws;
  float* cl    = (float*)(ws + 0);                   // 262144 B
  float* kc    = (float*)(ws + 262144);              // 262144 B
  float* sumP  = (float*)(ws + 524288);              // 4096 B
  float* sumQ  = (float*)(ws + 528384);              // 4096 B
  float* carry = (float*)(ws + 532480);              // 4096 B
  unsigned short* emb = (unsigned short*)(ws + 540672);            // 4 MB
  unsigned short* Bt  = (unsigned short*)(ws + 540672 + 4194304);  // 128 KB

  k_gates<<<dim3(512),  dim3(512), 0, stream>>>(x, inc_w, inc_b, reset_w, reset_b,
                                                out_incl, cl, kc, sumP, sumQ);
  k_scan2<<<dim3(129),  dim3(512), 0, stream>>>(sumP, sumQ, carry, read_w, Bt);
  k_emb  <<<dim3(2048), dim3(256), 0, stream>>>(cl, kc, carry, out_cnt, emb);
  k_gemm <<<dim3(8192), dim3(256), 0, stream>>>(emb, Bt, read_b, out);
}

// Round 2
// 264.500 us; speedup vs baseline: 1.0384x; 1.0384x over previous
//
#include <hip/hip_runtime.h>

#define B_    4
#define L_    8192
#define D_    1024
#define ROWS_ 32768
#define NCH_  128   // chunks of 64 rows per sequence

typedef __attribute__((ext_vector_type(8))) short  short8;
typedef __attribute__((ext_vector_type(4))) float  floatx4;

__device__ __forceinline__ unsigned short f2bf(float f){
  unsigned int u = __float_as_uint(f);
  u += 0x7fffu + ((u >> 16) & 1u);   // round-to-nearest-even
  return (unsigned short)(u >> 16);
}

// ---------------------------------------------------------------------------
// K1: gate GEMV (4 dots of length 1024 per row) + chunk-local scan (64 rows)
// grid 512 blocks (b,chunk), 512 threads (8 waves x 8 rows each)
// ---------------------------------------------------------------------------
__global__ __launch_bounds__(512) void k_gates(
    const float* __restrict__ x,
    const float* __restrict__ inc_w, const float* __restrict__ inc_b,
    const float* __restrict__ reset_w, const float* __restrict__ reset_b,
    float* __restrict__ out_incl,
    float* __restrict__ cl, float* __restrict__ kc,
    float* __restrict__ sumP, float* __restrict__ sumQ)
{
  __shared__ float s_keep[128];
  __shared__ float s_inc[128];
  const int blk  = blockIdx.x;
  const int b    = blk >> 7;          // /NCH_
  const int ch   = blk & 127;
  const int tid  = threadIdx.x;
  const int w    = tid >> 6;
  const int lane = tid & 63;

  // per-lane weights for d in {i*256 + 4*lane .. +3}, both k, both gates
  float4 wia[4], wib[4], wra[4], wrb[4];
  #pragma unroll
  for (int i = 0; i < 4; ++i){
    const int d0 = i*256 + lane*4;
    const float4* pi = (const float4*)(inc_w + d0*2);
    wia[i] = pi[0]; wib[i] = pi[1];
    const float4* pr = (const float4*)(reset_w + d0*2);
    wra[i] = pr[0]; wrb[i] = pr[1];
  }
  const float bi0 = inc_b[0], bi1 = inc_b[1];
  const float br0 = reset_b[0], br1 = reset_b[1];

  const int row0 = b*L_ + ch*64 + w*8;
  float4 xc[4], xn[4];
  {
    const float4* xr = (const float4*)(x + (size_t)row0 * D_);
    #pragma unroll
    for (int i = 0; i < 4; ++i) xc[i] = xr[i*64 + lane];
  }
  #pragma unroll
  for (int r = 0; r < 8; ++r){
    if (r < 7){  // prefetch next row while computing this one
      const float4* xr = (const float4*)(x + (size_t)(row0 + r + 1) * D_);
      #pragma unroll
      for (int i = 0; i < 4; ++i) xn[i] = xr[i*64 + lane];
    }
    float ai0=0.f, ai1=0.f, ar0=0.f, ar1=0.f;
    #pragma unroll
    for (int i = 0; i < 4; ++i){
      const float4 v = xc[i];
      ai0 += v.x*wia[i].x + v.y*wia[i].z + v.z*wib[i].x + v.w*wib[i].z;
      ai1 += v.x*wia[i].y + v.y*wia[i].w + v.z*wib[i].y + v.w*wib[i].w;
      ar0 += v.x*wra[i].x + v.y*wra[i].z + v.z*wrb[i].x + v.w*wrb[i].z;
      ar1 += v.x*wra[i].y + v.y*wra[i].w + v.z*wrb[i].y + v.w*wrb[i].w;
    }
    #pragma unroll
    for (int m = 1; m < 64; m <<= 1){
      ai0 += __shfl_xor(ai0, m);
      ai1 += __shfl_xor(ai1, m);
      ar0 += __shfl_xor(ar0, m);
      ar1 += __shfl_xor(ar1, m);
    }
    if (lane == 0){
      const int row = row0 + r;
      const float il0 = ai0 + bi0, il1 = ai1 + bi1;
      const float rl0 = ar0 + br0, rl1 = ar1 + br1;
      out_incl[(size_t)row*2 + 0] = il0;
      out_incl[(size_t)row*2 + 1] = il1;
      const int lr = w*8 + r;
      s_inc [lr*2+0] = 1.f / (1.f + __expf(-il0));
      s_inc [lr*2+1] = 1.f / (1.f + __expf(-il1));
      s_keep[lr*2+0] = 1.f - 1.f / (1.f + __expf(-rl0));
      s_keep[lr*2+1] = 1.f - 1.f / (1.f + __expf(-rl1));
    }
    #pragma unroll
    for (int i = 0; i < 4; ++i) xc[i] = xn[i];
  }
  __syncthreads();

  // chunk-local inclusive scan: wave 0 -> k=0, wave 1 -> k=1, lane j = local row j
  if (tid < 128){
    const int k = w;
    float P = s_keep[lane*2 + k];   // keep
    float Q = s_inc [lane*2 + k];   // inc
    #pragma unroll
    for (int ofs = 1; ofs < 64; ofs <<= 1){
      const float Pp = __shfl_up(P, ofs);
      const float Qp = __shfl_up(Q, ofs);
      if (lane >= ofs){ Q = Q + P * Qp; P = P * Pp; }
    }
    const int row = b*L_ + ch*64 + lane;
    cl[(size_t)row*2 + k] = Q;      // zero-state local counter
    kc[(size_t)row*2 + k] = P;      // cumulative keep product
    if (lane == 63){
      const int seq = b*2 + k;
      sumP[seq*NCH_ + ch] = P;
      sumQ[seq*NCH_ + ch] = Q;
    }
  }
}

// ---------------------------------------------------------------------------
// K2: block 0 scans the 128 chunk summaries per sequence (8 waves = 8 seqs)
//     blocks 1..128 transpose+convert read_w (64x1024 f32) -> Bt (1024x64 bf16)
// ---------------------------------------------------------------------------
__global__ __launch_bounds__(512) void k_scan2(
    const float* __restrict__ sumP, const float* __restrict__ sumQ,
    float* __restrict__ carry,
    const float* __restrict__ read_w, unsigned short* __restrict__ Bt)
{
  if (blockIdx.x == 0){
    const int tid  = threadIdx.x;
    const int seq  = tid >> 6;     // 0..7 = (b*2+k)
    const int lane = tid & 63;
    const float* P0 = sumP + seq*NCH_;
    const float* Q0 = sumQ + seq*NCH_;
    float P = P0[lane], Q = Q0[lane];
    #pragma unroll
    for (int ofs = 1; ofs < 64; ofs <<= 1){
      const float Pp = __shfl_up(P, ofs);
      const float Qp = __shfl_up(Q, ofs);
      if (lane >= ofs){ Q = Q + P * Qp; P = P * Pp; }
    }
    if (lane == 0) carry[seq*NCH_ + 0] = 0.f;
    carry[seq*NCH_ + lane + 1] = Q;                // chunks 1..64
    const float Pc = __shfl(P, 63);
    const float Qc = __shfl(Q, 63);
    float P2 = P0[64 + lane], Q2 = Q0[64 + lane];
    #pragma unroll
    for (int ofs = 1; ofs < 64; ofs <<= 1){
      const float Pp = __shfl_up(P2, ofs);
      const float Qp = __shfl_up(Q2, ofs);
      if (lane >= ofs){ Q2 = Q2 + P2 * Qp; P2 = P2 * Pp; }
    }
    Q2 = Q2 + P2 * Qc;                             // fold in first-half total
    if (lane < 63) carry[seq*NCH_ + 65 + lane] = Q2;   // chunks 65..127
  } else {
    const int idx = (blockIdx.x - 1)*512 + threadIdx.x;  // 0..65535
    const int n  = idx >> 6;
    const int kk = idx & 63;
    Bt[idx] = f2bf(read_w[(size_t)kk*D_ + n]);
  }
}

// ---------------------------------------------------------------------------
// K3 (fused emb+GEMM): per 16-row tile, compute counters -> sinusoidal A-frag
// in-register (bf16), then injection = A(16x64) @ read_w(64x1024) + read_b.
// block = 4 waves; wave computes 16 rows x 256 cols (16 16x16 tiles, 2 k-steps)
// Also writes the counters output (wave 0, lanes 0-15).
// ---------------------------------------------------------------------------
__global__ __launch_bounds__(256) void k_fused(
    const float* __restrict__ cl, const float* __restrict__ kc,
    const float* __restrict__ carry,
    const unsigned short* __restrict__ Bt,
    const float* __restrict__ read_b,
    float* __restrict__ out_cnt, float* __restrict__ out)
{
  const int tid  = threadIdx.x;
  const int w    = tid >> 6;
  const int lane = tid & 63;
  const int rowBase = blockIdx.x * 16;        // 2048 row tiles
  const int m    = lane & 15;
  const int quad = lane >> 4;

  // ---- counters for this lane's row ----
  const int row = rowBase + m;
  const int b   = row >> 13;                  // /L_
  const int ch  = (row & (L_ - 1)) >> 6;
  const float2 clv = *(const float2*)(cl + (size_t)row*2);
  const float2 kcv = *(const float2*)(kc + (size_t)row*2);
  const float c0 = clv.x + kcv.x * carry[(b*2+0)*NCH_ + ch];
  const float c1 = clv.y + kcv.y * carry[(b*2+1)*NCH_ + ch];
  if (w == 0 && lane < 16){
    ((float2*)out_cnt)[row] = make_float2(c0, c1);
  }

  // ---- A fragments in-register ----
  // k-step 0: emb col = quad*8+j  (counter k=0); k-step 1: col = 32+quad*8+j (k=1)
  // f = (quad&1)*8 + j, trig = quad>>1 (0=sin, 1=cos)
  const float TWO_PI_INV = 0.15915494309189535f;
  const float STEP = 0.5743491774985175f;        // 2^-0.8
  float invf = (quad & 1) ? 0.011841535573494211f /* 2^-6.4 */ : 1.0f;
  const bool use_cos = (quad >> 1) != 0;
  short8 a0, a1;
  #pragma unroll
  for (int j = 0; j < 8; ++j){
    float r0 = c0 * invf * TWO_PI_INV; r0 -= floorf(r0);
    float r1 = c1 * invf * TWO_PI_INV; r1 -= floorf(r1);
    const float e0 = use_cos ? __builtin_amdgcn_cosf(r0) : __builtin_amdgcn_sinf(r0);
    const float e1 = use_cos ? __builtin_amdgcn_cosf(r1) : __builtin_amdgcn_sinf(r1);
    a0[j] = (short)f2bf(e0);
    a1[j] = (short)f2bf(e1);
    invf *= STEP;
  }

  // ---- MFMA over 16 col tiles (256 cols per wave) ----
  const int colBase = w * 256;
  floatx4 acc[16];
  #pragma unroll
  for (int ct = 0; ct < 16; ++ct) acc[ct] = (floatx4){0.f,0.f,0.f,0.f};
  #pragma unroll
  for (int ct = 0; ct < 16; ++ct){
    const int n = colBase + ct*16 + m;
    const short8* bp = (const short8*)(Bt + (size_t)n * 64);
    const short8 b0 = bp[quad];
    const short8 b1 = bp[4 + quad];
    acc[ct] = __builtin_amdgcn_mfma_f32_16x16x32_bf16(a0, b0, acc[ct], 0, 0, 0);
    acc[ct] = __builtin_amdgcn_mfma_f32_16x16x32_bf16(a1, b1, acc[ct], 0, 0, 0);
  }

  // ---- epilogue: bias + store (C/D: col=lane&15, row=quad*4+reg) ----
  #pragma unroll
  for (int ct = 0; ct < 16; ++ct){
    const int col  = colBase + ct*16 + m;
    const float bias = read_b[col];
    #pragma unroll
    for (int r = 0; r < 4; ++r){
      const int orow = rowBase + quad*4 + r;
      out[(size_t)orow*D_ + col] = acc[ct][r] + bias;
    }
  }
}

// ---------------------------------------------------------------------------
extern "C" void kernel_launch(void* const* d_in, const int* in_sizes, int n_in,
                              void* d_out, int out_size, void* d_ws, size_t ws_size,
                              hipStream_t stream) {
  const float* x       = (const float*)d_in[0];
  const float* inc_w   = (const float*)d_in[1];
  const float* inc_b   = (const float*)d_in[2];
  const float* reset_w = (const float*)d_in[3];
  const float* reset_b = (const float*)d_in[4];
  const float* read_w  = (const float*)d_in[5];
  const float* read_b  = (const float*)d_in[6];

  float* out      = (float*)d_out;
  float* out_incl = out + (size_t)ROWS_ * D_;        // 33554432
  float* out_cnt  = out_incl + ROWS_ * 2;            // +65536

  char* ws = (char*)d_ws;
  float* cl    = (float*)(ws + 0);                   // 262144 B
  float* kc    = (float*)(ws + 262144);              // 262144 B
  float* sumP  = (float*)(ws + 524288);              // 4096 B
  float* sumQ  = (float*)(ws + 528384);              // 4096 B
  float* carry = (float*)(ws + 532480);              // 4096 B
  unsigned short* Bt  = (unsigned short*)(ws + 540672);  // 128 KB

  k_gates<<<dim3(512),  dim3(512), 0, stream>>>(x, inc_w, inc_b, reset_w, reset_b,
                                                out_incl, cl, kc, sumP, sumQ);
  k_scan2<<<dim3(129),  dim3(512), 0, stream>>>(sumP, sumQ, carry, read_w, Bt);
  k_fused<<<dim3(2048), dim3(256), 0, stream>>>(cl, kc, carry, Bt, read_b,
                                                out_cnt, out);
}

// Round 3
// 263.776 us; speedup vs baseline: 1.0413x; 1.0027x over previous
//
#include <hip/hip_runtime.h>

#define B_    4
#define L_    8192
#define D_    1024
#define ROWS_ 32768
#define NCH_  128   // chunks of 64 rows per sequence

typedef __attribute__((ext_vector_type(8))) short  short8;
typedef __attribute__((ext_vector_type(4))) float  floatx4;

__device__ __forceinline__ unsigned short f2bf(float f){
  unsigned int u = __float_as_uint(f);
  u += 0x7fffu + ((u >> 16) & 1u);   // round-to-nearest-even
  return (unsigned short)(u >> 16);
}

// ---------------------------------------------------------------------------
// K1: gate GEMV (4 dots of length 1024 per row) + chunk-local scan (64 rows)
// blocks 0..511: (b,chunk), 512 threads (8 waves x 8 rows each)
// blocks 512..543: transpose+convert read_w (64x1024 f32) -> Bt (1024x64 bf16)
// ---------------------------------------------------------------------------
__global__ __launch_bounds__(512) void k_gates(
    const float* __restrict__ x,
    const float* __restrict__ inc_w, const float* __restrict__ inc_b,
    const float* __restrict__ reset_w, const float* __restrict__ reset_b,
    float* __restrict__ out_incl,
    float* __restrict__ cl, float* __restrict__ kc,
    float* __restrict__ sumP, float* __restrict__ sumQ,
    const float* __restrict__ read_w, unsigned short* __restrict__ Bt)
{
  const int blk  = blockIdx.x;
  if (blk >= 512){
    // Bt build: 32 blocks x 512 threads x 4 elements = 65536
    const int idx0 = ((blk - 512)*512 + threadIdx.x)*4;   // multiple of 4
    const int n  = idx0 >> 6;            // same for all 4 (4 | 64)
    const int kk = idx0 & 63;
    ushort4 v;
    v.x = f2bf(read_w[(size_t)(kk+0)*D_ + n]);
    v.y = f2bf(read_w[(size_t)(kk+1)*D_ + n]);
    v.z = f2bf(read_w[(size_t)(kk+2)*D_ + n]);
    v.w = f2bf(read_w[(size_t)(kk+3)*D_ + n]);
    *(ushort4*)(Bt + idx0) = v;
    return;
  }

  __shared__ float s_keep[128];
  __shared__ float s_inc[128];
  const int b    = blk >> 7;          // /NCH_
  const int ch   = blk & 127;
  const int tid  = threadIdx.x;
  const int w    = tid >> 6;
  const int lane = tid & 63;

  // per-lane weights for d in {i*256 + 4*lane .. +3}, both k, both gates
  float4 wia[4], wib[4], wra[4], wrb[4];
  #pragma unroll
  for (int i = 0; i < 4; ++i){
    const int d0 = i*256 + lane*4;
    const float4* pi = (const float4*)(inc_w + d0*2);
    wia[i] = pi[0]; wib[i] = pi[1];
    const float4* pr = (const float4*)(reset_w + d0*2);
    wra[i] = pr[0]; wrb[i] = pr[1];
  }
  const float bi0 = inc_b[0], bi1 = inc_b[1];
  const float br0 = reset_b[0], br1 = reset_b[1];

  const int row0 = b*L_ + ch*64 + w*8;
  float4 xc[4], xn[4];
  {
    const float4* xr = (const float4*)(x + (size_t)row0 * D_);
    #pragma unroll
    for (int i = 0; i < 4; ++i) xc[i] = xr[i*64 + lane];
  }
  #pragma unroll
  for (int r = 0; r < 8; ++r){
    if (r < 7){  // prefetch next row while computing this one
      const float4* xr = (const float4*)(x + (size_t)(row0 + r + 1) * D_);
      #pragma unroll
      for (int i = 0; i < 4; ++i) xn[i] = xr[i*64 + lane];
    }
    float ai0=0.f, ai1=0.f, ar0=0.f, ar1=0.f;
    #pragma unroll
    for (int i = 0; i < 4; ++i){
      const float4 v = xc[i];
      ai0 += v.x*wia[i].x + v.y*wia[i].z + v.z*wib[i].x + v.w*wib[i].z;
      ai1 += v.x*wia[i].y + v.y*wia[i].w + v.z*wib[i].y + v.w*wib[i].w;
      ar0 += v.x*wra[i].x + v.y*wra[i].z + v.z*wrb[i].x + v.w*wrb[i].z;
      ar1 += v.x*wra[i].y + v.y*wra[i].w + v.z*wrb[i].y + v.w*wrb[i].w;
    }
    #pragma unroll
    for (int m = 1; m < 64; m <<= 1){
      ai0 += __shfl_xor(ai0, m);
      ai1 += __shfl_xor(ai1, m);
      ar0 += __shfl_xor(ar0, m);
      ar1 += __shfl_xor(ar1, m);
    }
    if (lane == 0){
      const int row = row0 + r;
      const float il0 = ai0 + bi0, il1 = ai1 + bi1;
      const float rl0 = ar0 + br0, rl1 = ar1 + br1;
      out_incl[(size_t)row*2 + 0] = il0;
      out_incl[(size_t)row*2 + 1] = il1;
      const int lr = w*8 + r;
      s_inc [lr*2+0] = 1.f / (1.f + __expf(-il0));
      s_inc [lr*2+1] = 1.f / (1.f + __expf(-il1));
      s_keep[lr*2+0] = 1.f - 1.f / (1.f + __expf(-rl0));
      s_keep[lr*2+1] = 1.f - 1.f / (1.f + __expf(-rl1));
    }
    #pragma unroll
    for (int i = 0; i < 4; ++i) xc[i] = xn[i];
  }
  __syncthreads();

  // chunk-local inclusive scan: wave 0 -> k=0, wave 1 -> k=1, lane j = local row j
  if (tid < 128){
    const int k = w;
    float P = s_keep[lane*2 + k];   // keep
    float Q = s_inc [lane*2 + k];   // inc
    #pragma unroll
    for (int ofs = 1; ofs < 64; ofs <<= 1){
      const float Pp = __shfl_up(P, ofs);
      const float Qp = __shfl_up(Q, ofs);
      if (lane >= ofs){ Q = Q + P * Qp; P = P * Pp; }
    }
    const int row = b*L_ + ch*64 + lane;
    cl[(size_t)row*2 + k] = Q;      // zero-state local counter
    kc[(size_t)row*2 + k] = P;      // cumulative keep product
    if (lane == 63){
      const int seq = b*2 + k;
      sumP[seq*NCH_ + ch] = P;
      sumQ[seq*NCH_ + ch] = Q;
    }
  }
}

// ---------------------------------------------------------------------------
// K2 (fused carry-scan + emb + GEMM): per 16-row tile,
//   waves 0/1 redundantly scan the 128 chunk summaries of this block's two
//   sequences and extract the exclusive carry for this block's chunk;
//   then counters -> sinusoidal A-frag in-register (bf16) ->
//   injection = A(16x64) @ read_w(64x1024) + read_b.
// block = 4 waves; wave computes 16 rows x 256 cols (16 16x16 tiles, 2 k-steps)
// Also writes the counters output (wave 0, lanes 0-15).
// ---------------------------------------------------------------------------
__global__ __launch_bounds__(256) void k_fused(
    const float* __restrict__ cl, const float* __restrict__ kc,
    const float* __restrict__ sumP, const float* __restrict__ sumQ,
    const unsigned short* __restrict__ Bt,
    const float* __restrict__ read_b,
    float* __restrict__ out_cnt, float* __restrict__ out)
{
  __shared__ float s_carry[2];
  const int tid  = threadIdx.x;
  const int w    = tid >> 6;
  const int lane = tid & 63;
  const int rowBase = blockIdx.x * 16;        // 2048 row tiles
  const int b   = rowBase >> 13;              // /L_
  const int ch  = (rowBase & (L_ - 1)) >> 6;  // same chunk for all 16 rows
  const int m    = lane & 15;
  const int quad = lane >> 4;

  // ---- exclusive carry for chunk ch of sequences (b,k=0) and (b,k=1) ----
  if (w < 2){
    const int seq = b*2 + w;
    const float* P0 = sumP + seq*NCH_;
    const float* Q0 = sumQ + seq*NCH_;
    float P = P0[lane], Q = Q0[lane];
    #pragma unroll
    for (int ofs = 1; ofs < 64; ofs <<= 1){
      const float Pp = __shfl_up(P, ofs);
      const float Qp = __shfl_up(Q, ofs);
      if (lane >= ofs){ Q = Q + P * Qp; P = P * Pp; }
    }
    float carry = 0.f;
    if (ch > 0 && ch <= 64) carry = __shfl(Q, ch-1);
    const float Qc = __shfl(Q, 63);
    float P2 = P0[64 + lane], Q2 = Q0[64 + lane];
    #pragma unroll
    for (int ofs = 1; ofs < 64; ofs <<= 1){
      const float Pp = __shfl_up(P2, ofs);
      const float Qp = __shfl_up(Q2, ofs);
      if (lane >= ofs){ Q2 = Q2 + P2 * Qp; P2 = P2 * Pp; }
    }
    Q2 = Q2 + P2 * Qc;                        // fold in first-half total
    if (ch >= 65) carry = __shfl(Q2, ch-65);
    if (lane == 0) s_carry[w] = carry;
  }
  __syncthreads();
  const float carry0 = s_carry[0];
  const float carry1 = s_carry[1];

  // ---- counters for this lane's row ----
  const int row = rowBase + m;
  const float2 clv = *(const float2*)(cl + (size_t)row*2);
  const float2 kcv = *(const float2*)(kc + (size_t)row*2);
  const float c0 = clv.x + kcv.x * carry0;
  const float c1 = clv.y + kcv.y * carry1;
  if (w == 0 && lane < 16){
    ((float2*)out_cnt)[row] = make_float2(c0, c1);
  }

  // ---- A fragments in-register ----
  // k-step 0: emb col = quad*8+j  (counter k=0); k-step 1: col = 32+quad*8+j (k=1)
  // f = (quad&1)*8 + j, trig = quad>>1 (0=sin, 1=cos)
  const float TWO_PI_INV = 0.15915494309189535f;
  const float STEP = 0.5743491774985175f;        // 2^-0.8
  float invf = (quad & 1) ? 0.011841535573494211f /* 2^-6.4 */ : 1.0f;
  const bool use_cos = (quad >> 1) != 0;
  short8 a0, a1;
  #pragma unroll
  for (int j = 0; j < 8; ++j){
    float r0 = c0 * invf * TWO_PI_INV; r0 -= floorf(r0);
    float r1 = c1 * invf * TWO_PI_INV; r1 -= floorf(r1);
    const float e0 = use_cos ? __builtin_amdgcn_cosf(r0) : __builtin_amdgcn_sinf(r0);
    const float e1 = use_cos ? __builtin_amdgcn_cosf(r1) : __builtin_amdgcn_sinf(r1);
    a0[j] = (short)f2bf(e0);
    a1[j] = (short)f2bf(e1);
    invf *= STEP;
  }

  // ---- MFMA over 16 col tiles (256 cols per wave) ----
  const int colBase = w * 256;
  floatx4 acc[16];
  #pragma unroll
  for (int ct = 0; ct < 16; ++ct) acc[ct] = (floatx4){0.f,0.f,0.f,0.f};
  #pragma unroll
  for (int ct = 0; ct < 16; ++ct){
    const int n = colBase + ct*16 + m;
    const short8* bp = (const short8*)(Bt + (size_t)n * 64);
    const short8 b0 = bp[quad];
    const short8 b1 = bp[4 + quad];
    acc[ct] = __builtin_amdgcn_mfma_f32_16x16x32_bf16(a0, b0, acc[ct], 0, 0, 0);
    acc[ct] = __builtin_amdgcn_mfma_f32_16x16x32_bf16(a1, b1, acc[ct], 0, 0, 0);
  }

  // ---- epilogue: bias + store (C/D: col=lane&15, row=quad*4+reg) ----
  #pragma unroll
  for (int ct = 0; ct < 16; ++ct){
    const int col  = colBase + ct*16 + m;
    const float bias = read_b[col];
    #pragma unroll
    for (int r = 0; r < 4; ++r){
      const int orow = rowBase + quad*4 + r;
      out[(size_t)orow*D_ + col] = acc[ct][r] + bias;
    }
  }
}

// ---------------------------------------------------------------------------
extern "C" void kernel_launch(void* const* d_in, const int* in_sizes, int n_in,
                              void* d_out, int out_size, void* d_ws, size_t ws_size,
                              hipStream_t stream) {
  const float* x       = (const float*)d_in[0];
  const float* inc_w   = (const float*)d_in[1];
  const float* inc_b   = (const float*)d_in[2];
  const float* reset_w = (const float*)d_in[3];
  const float* reset_b = (const float*)d_in[4];
  const float* read_w  = (const float*)d_in[5];
  const float* read_b  = (const float*)d_in[6];

  float* out      = (float*)d_out;
  float* out_incl = out + (size_t)ROWS_ * D_;        // 33554432
  float* out_cnt  = out_incl + ROWS_ * 2;            // +65536

  char* ws = (char*)d_ws;
  float* cl    = (float*)(ws + 0);                   // 262144 B
  float* kc    = (float*)(ws + 262144);              // 262144 B
  float* sumP  = (float*)(ws + 524288);              // 4096 B
  float* sumQ  = (float*)(ws + 528384);              // 4096 B
  unsigned short* Bt  = (unsigned short*)(ws + 532480);  // 128 KB

  k_gates<<<dim3(544),  dim3(512), 0, stream>>>(x, inc_w, inc_b, reset_w, reset_b,
                                                out_incl, cl, kc, sumP, sumQ,
                                                read_w, Bt);
  k_fused<<<dim3(2048), dim3(256), 0, stream>>>(cl, kc, sumP, sumQ, Bt, read_b,
                                                out_cnt, out);
}